// Round 1
// baseline (882.780 us; speedup 1.0000x reference)
//
#include <hip/hip_runtime.h>

#define M 8192
#define N 4096
#define K 4096
#define BM 128
#define BN 128
#define BK 32
#define LDK 40   // padded LDS K-stride (elements): 80 B -> 2-way bank aliasing (free)
#define NK (K / BK)

typedef __attribute__((ext_vector_type(8))) short bf16x8;
typedef __attribute__((ext_vector_type(4))) float f32x4;

__device__ __forceinline__ unsigned short f2bf(float f) {
    unsigned u = __float_as_uint(f);
    u += 0x7fffu + ((u >> 16) & 1u);   // round-to-nearest-even
    return (unsigned short)(u >> 16);
}

__device__ __forceinline__ void cvt_store(short* dst, const f32x4* r) {
    bf16x8 v0, v1;
    #pragma unroll
    for (int i = 0; i < 4; ++i) {
        v0[i]     = (short)f2bf(r[0][i]);
        v0[4 + i] = (short)f2bf(r[1][i]);
        v1[i]     = (short)f2bf(r[2][i]);
        v1[4 + i] = (short)f2bf(r[3][i]);
    }
    *(bf16x8*)dst       = v0;
    *(bf16x8*)(dst + 8) = v1;
}

__global__ __launch_bounds__(256) void gemm_rowmax(
    const float* __restrict__ x, const float* __restrict__ w,
    const float* __restrict__ bias, float* __restrict__ out,
    int* __restrict__ rowmax)
{
    __shared__ __align__(16) short As[2][BM * LDK];
    __shared__ __align__(16) short Bs[2][BN * LDK];

    const int bid = blockIdx.x;
    const int tm = bid % (M / BM);
    const int tn = bid / (M / BM);
    const int bm = tm * BM, bn = tn * BN;

    const int t    = threadIdx.x;     // 0..255
    const int w_id = t >> 6;          // wave 0..3
    const int l    = t & 63;
    const int wr   = w_id >> 1;       // wave row 0..1 (64 rows each)
    const int wc   = w_id & 1;        // wave col 0..1 (64 cols each)
    const int lr   = l & 15;
    const int g    = l >> 4;
    const int lk   = g * 8;           // k-offset of this lane's fragment

    // staging map: thread t handles row t/2, 16-element k-chunk (t&1)*16
    const int srow = t >> 1;
    const int scol = (t & 1) << 4;

    const float* gA = x + (size_t)(bm + srow) * K + scol;
    const float* gB = w + (size_t)(bn + srow) * K + scol;

    f32x4 acc[4][4];
    #pragma unroll
    for (int m = 0; m < 4; ++m)
        #pragma unroll
        for (int n = 0; n < 4; ++n)
            acc[m][n] = (f32x4){0.f, 0.f, 0.f, 0.f};

    // prologue: stage K-tile 0 into buffer 0
    {
        f32x4 ra[4], rb[4];
        #pragma unroll
        for (int i = 0; i < 4; ++i) {
            ra[i] = *(const f32x4*)(gA + i * 4);
            rb[i] = *(const f32x4*)(gB + i * 4);
        }
        cvt_store(&As[0][srow * LDK + scol], ra);
        cvt_store(&Bs[0][srow * LDK + scol], rb);
    }
    __syncthreads();

    int cur = 0;
    for (int kt = 0; kt < NK; ++kt) {
        f32x4 ra[4], rb[4];
        const bool pf = (kt + 1 < NK);
        if (pf) {
            const float* pA = gA + (size_t)(kt + 1) * BK;
            const float* pB = gB + (size_t)(kt + 1) * BK;
            #pragma unroll
            for (int i = 0; i < 4; ++i) {
                ra[i] = *(const f32x4*)(pA + i * 4);
                rb[i] = *(const f32x4*)(pB + i * 4);
            }
        }

        bf16x8 af[4], bf[4];
        #pragma unroll
        for (int m = 0; m < 4; ++m)
            af[m] = *(const bf16x8*)&As[cur][(wr * 64 + m * 16 + lr) * LDK + lk];
        #pragma unroll
        for (int n = 0; n < 4; ++n)
            bf[n] = *(const bf16x8*)&Bs[cur][(wc * 64 + n * 16 + lr) * LDK + lk];

        #pragma unroll
        for (int m = 0; m < 4; ++m)
            #pragma unroll
            for (int n = 0; n < 4; ++n)
                acc[m][n] = __builtin_amdgcn_mfma_f32_16x16x32_bf16(
                    af[m], bf[n], acc[m][n], 0, 0, 0);

        if (pf) {
            cvt_store(&As[cur ^ 1][srow * LDK + scol], ra);
            cvt_store(&Bs[cur ^ 1][srow * LDK + scol], rb);
        }
        __syncthreads();
        cur ^= 1;
    }

    // epilogue: bias, store h, per-row |max| -> atomicMax
    float bv[4];
    #pragma unroll
    for (int n = 0; n < 4; ++n)
        bv[n] = bias[bn + wc * 64 + n * 16 + lr];

    #pragma unroll
    for (int m = 0; m < 4; ++m) {
        #pragma unroll
        for (int r = 0; r < 4; ++r) {
            const int row = bm + wr * 64 + m * 16 + g * 4 + r;
            float amax = 0.f;
            #pragma unroll
            for (int n = 0; n < 4; ++n) {
                const float v = acc[m][n][r] + bv[n];
                out[(size_t)row * N + (bn + wc * 64 + n * 16 + lr)] = v;
                amax = fmaxf(amax, fabsf(v));
            }
            // reduce over the 16 lanes (lr = 0..15) that share this row
            #pragma unroll
            for (int off = 1; off < 16; off <<= 1)
                amax = fmaxf(amax, __shfl_xor(amax, off));
            if (lr == 0)
                atomicMax(rowmax + row, __float_as_int(amax));
        }
    }
}

__global__ __launch_bounds__(256) void quant_relu(
    float* __restrict__ y, const int* __restrict__ rowmax)
{
    const int nvec = (M * N) / 4;   // float4 count; 1024 per row
    for (int i = blockIdx.x * blockDim.x + threadIdx.x; i < nvec;
         i += gridDim.x * blockDim.x) {
        const int row = i >> 10;
        const float mx = __int_as_float(rowmax[row]);
        f32x4 v = ((const f32x4*)y)[i];
        if (mx > 0.f) {
            const int e = ilogbf(mx);            // floor(log2(mx)) for normal mx>0
            const float step = ldexpf(1.0f, e - 6);   // 2^(e + 2 - wl), wl=8
            const float inv  = ldexpf(1.0f, 6 - e);   // exact reciprocal (pow2)
            #pragma unroll
            for (int j = 0; j < 4; ++j)
                v[j] = floorf(v[j] * inv + 0.5f) * step;
        }
        #pragma unroll
        for (int j = 0; j < 4; ++j)
            v[j] = fmaxf(v[j], 0.f);
        ((f32x4*)y)[i] = v;
    }
}

extern "C" void kernel_launch(void* const* d_in, const int* in_sizes, int n_in,
                              void* d_out, int out_size, void* d_ws, size_t ws_size,
                              hipStream_t stream) {
    const float* x = (const float*)d_in[0];
    const float* w = (const float*)d_in[1];
    const float* b = (const float*)d_in[2];
    float* out = (float*)d_out;
    int* rowmax = (int*)d_ws;

    hipMemsetAsync(rowmax, 0, M * sizeof(int), stream);

    dim3 grid((M / BM) * (N / BN));   // 2048 blocks
    gemm_rowmax<<<grid, 256, 0, stream>>>(x, w, b, out, rowmax);
    quant_relu<<<2048, 256, 0, stream>>>(out, rowmax);
}

// Round 2
// 689.018 us; speedup vs baseline: 1.2812x; 1.2812x over previous
//
#include <hip/hip_runtime.h>

#define M 8192
#define N 4096
#define K 4096
#define BM 128
#define BN 128
#define BK 32
#define NK (K / BK)

typedef __attribute__((ext_vector_type(8))) short bf16x8;
typedef __attribute__((ext_vector_type(4))) float f32x4;

typedef __attribute__((address_space(1))) const unsigned GU;
typedef __attribute__((address_space(3))) unsigned LU;

__device__ __forceinline__ unsigned short f2bf(float f) {
    unsigned u = __float_as_uint(f);
    u += 0x7fffu + ((u >> 16) & 1u);   // round-to-nearest-even
    return (unsigned short)(u >> 16);
}

// ---------------- fp32 -> bf16 convert (8 elems/thread/iter) ----------------
__global__ __launch_bounds__(256) void cvt_bf16(const float* __restrict__ src,
                                                unsigned short* __restrict__ dst,
                                                int n8) {
    const int stride = gridDim.x * blockDim.x;
    for (int i = blockIdx.x * blockDim.x + threadIdx.x; i < n8; i += stride) {
        f32x4 a = ((const f32x4*)src)[2 * i];
        f32x4 b = ((const f32x4*)src)[2 * i + 1];
        bf16x8 v;
        #pragma unroll
        for (int j = 0; j < 4; ++j) {
            v[j]     = (short)f2bf(a[j]);
            v[4 + j] = (short)f2bf(b[j]);
        }
        ((bf16x8*)dst)[i] = v;
    }
}

// ---------------- m97-structure bf16 GEMM + bias + row |max| ----------------
__global__ __launch_bounds__(256) void gemm_bf16(
    const unsigned short* __restrict__ xb, const unsigned short* __restrict__ wb,
    const float* __restrict__ bias, float* __restrict__ out,
    int* __restrict__ rowmax)
{
    __shared__ __align__(16) short As[2][BM * BK];   // linear: required by global_load_lds
    __shared__ __align__(16) short Bs[2][BN * BK];

    const int bid = blockIdx.x;
    const int tm = bid % (M / BM);
    const int tn = bid / (M / BM);
    const int bm = tm * BM, bn = tn * BN;

    const int t    = threadIdx.x;
    const int w_id = t >> 6;
    const int l    = t & 63;
    const int wr   = w_id >> 1;       // wave row 0..1
    const int wc   = w_id & 1;        // wave col 0..1
    const int lr   = l & 15;
    const int g    = l >> 4;
    const int lk   = g * 8;

    // staging map: chunk ch = 2*w_id + c covers rows ch*16..ch*16+15 (1024 B, 64 B/row)
    // lane l: global row-in-chunk = l/4, k-col = (l&3)*8; HW writes LDS base + l*16
    const int srow  = l >> 2;
    const int skcol = (l & 3) * 8;

    const unsigned short* gA = xb + (size_t)bm * K;
    const unsigned short* gB = wb + (size_t)bn * K;

    f32x4 acc[4][4];
    #pragma unroll
    for (int m = 0; m < 4; ++m)
        #pragma unroll
        for (int n = 0; n < 4; ++n)
            acc[m][n] = (f32x4){0.f, 0.f, 0.f, 0.f};

    auto stage = [&](int buf, int kt) {
        #pragma unroll
        for (int c = 0; c < 2; ++c) {
            const int ch = w_id * 2 + c;
            const unsigned short* ga =
                gA + (size_t)(ch * 16 + srow) * K + kt * BK + skcol;
            const unsigned short* gb =
                gB + (size_t)(ch * 16 + srow) * K + kt * BK + skcol;
            __builtin_amdgcn_global_load_lds((const GU*)ga, (LU*)(&As[buf][ch * 512]),
                                             16, 0, 0);
            __builtin_amdgcn_global_load_lds((const GU*)gb, (LU*)(&Bs[buf][ch * 512]),
                                             16, 0, 0);
        }
    };

    stage(0, 0);
    __syncthreads();   // drains vmcnt before first read

    int cur = 0;
    for (int kt = 0; kt < NK; ++kt) {
        if (kt + 1 < NK) stage(cur ^ 1, kt + 1);

        bf16x8 af[4], bfr[4];
        #pragma unroll
        for (int m = 0; m < 4; ++m)
            af[m] = *(const bf16x8*)&As[cur][(wr * 64 + m * 16 + lr) * BK + lk];
        #pragma unroll
        for (int n = 0; n < 4; ++n)
            bfr[n] = *(const bf16x8*)&Bs[cur][(wc * 64 + n * 16 + lr) * BK + lk];

        #pragma unroll
        for (int m = 0; m < 4; ++m)
            #pragma unroll
            for (int n = 0; n < 4; ++n)
                acc[m][n] = __builtin_amdgcn_mfma_f32_16x16x32_bf16(
                    af[m], bfr[n], acc[m][n], 0, 0, 0);

        __syncthreads();   // compute done on cur AND stage into cur^1 drained
        cur ^= 1;
    }

    // epilogue: bias, store h, per-row |max| -> atomicMax
    float bv[4];
    #pragma unroll
    for (int n = 0; n < 4; ++n)
        bv[n] = bias[bn + wc * 64 + n * 16 + lr];

    #pragma unroll
    for (int m = 0; m < 4; ++m) {
        #pragma unroll
        for (int r = 0; r < 4; ++r) {
            const int row = bm + wr * 64 + m * 16 + g * 4 + r;
            float amax = 0.f;
            #pragma unroll
            for (int n = 0; n < 4; ++n) {
                const float v = acc[m][n][r] + bv[n];
                out[(size_t)row * N + (bn + wc * 64 + n * 16 + lr)] = v;
                amax = fmaxf(amax, fabsf(v));
            }
            #pragma unroll
            for (int off = 1; off < 16; off <<= 1)
                amax = fmaxf(amax, __shfl_xor(amax, off));
            if (lr == 0)
                atomicMax(rowmax + row, __float_as_int(amax));
        }
    }
}

// ---------------- fallback: fused fp32-staging GEMM (round-1, verified) ----------------
__device__ __forceinline__ void cvt_store(short* dst, const f32x4* r) {
    bf16x8 v0, v1;
    #pragma unroll
    for (int i = 0; i < 4; ++i) {
        v0[i]     = (short)f2bf(r[0][i]);
        v0[4 + i] = (short)f2bf(r[1][i]);
        v1[i]     = (short)f2bf(r[2][i]);
        v1[4 + i] = (short)f2bf(r[3][i]);
    }
    *(bf16x8*)dst       = v0;
    *(bf16x8*)(dst + 8) = v1;
}

#define LDK 40
__global__ __launch_bounds__(256) void gemm_rowmax(
    const float* __restrict__ x, const float* __restrict__ w,
    const float* __restrict__ bias, float* __restrict__ out,
    int* __restrict__ rowmax)
{
    __shared__ __align__(16) short As[2][BM * LDK];
    __shared__ __align__(16) short Bs[2][BN * LDK];

    const int bid = blockIdx.x;
    const int tm = bid % (M / BM);
    const int tn = bid / (M / BM);
    const int bm = tm * BM, bn = tn * BN;

    const int t    = threadIdx.x;
    const int w_id = t >> 6;
    const int l    = t & 63;
    const int wr   = w_id >> 1;
    const int wc   = w_id & 1;
    const int lr   = l & 15;
    const int g    = l >> 4;
    const int lk   = g * 8;

    const int srow = t >> 1;
    const int scol = (t & 1) << 4;

    const float* gA = x + (size_t)(bm + srow) * K + scol;
    const float* gB = w + (size_t)(bn + srow) * K + scol;

    f32x4 acc[4][4];
    #pragma unroll
    for (int m = 0; m < 4; ++m)
        #pragma unroll
        for (int n = 0; n < 4; ++n)
            acc[m][n] = (f32x4){0.f, 0.f, 0.f, 0.f};

    {
        f32x4 ra[4], rb[4];
        #pragma unroll
        for (int i = 0; i < 4; ++i) {
            ra[i] = *(const f32x4*)(gA + i * 4);
            rb[i] = *(const f32x4*)(gB + i * 4);
        }
        cvt_store(&As[0][srow * LDK + scol], ra);
        cvt_store(&Bs[0][srow * LDK + scol], rb);
    }
    __syncthreads();

    int cur = 0;
    for (int kt = 0; kt < NK; ++kt) {
        f32x4 ra[4], rb[4];
        const bool pf = (kt + 1 < NK);
        if (pf) {
            const float* pA = gA + (size_t)(kt + 1) * BK;
            const float* pB = gB + (size_t)(kt + 1) * BK;
            #pragma unroll
            for (int i = 0; i < 4; ++i) {
                ra[i] = *(const f32x4*)(pA + i * 4);
                rb[i] = *(const f32x4*)(pB + i * 4);
            }
        }

        bf16x8 af[4], bfr[4];
        #pragma unroll
        for (int m = 0; m < 4; ++m)
            af[m] = *(const bf16x8*)&As[cur][(wr * 64 + m * 16 + lr) * LDK + lk];
        #pragma unroll
        for (int n = 0; n < 4; ++n)
            bfr[n] = *(const bf16x8*)&Bs[cur][(wc * 64 + n * 16 + lr) * LDK + lk];

        #pragma unroll
        for (int m = 0; m < 4; ++m)
            #pragma unroll
            for (int n = 0; n < 4; ++n)
                acc[m][n] = __builtin_amdgcn_mfma_f32_16x16x32_bf16(
                    af[m], bfr[n], acc[m][n], 0, 0, 0);

        if (pf) {
            cvt_store(&As[cur ^ 1][srow * LDK + scol], ra);
            cvt_store(&Bs[cur ^ 1][srow * LDK + scol], rb);
        }
        __syncthreads();
        cur ^= 1;
    }

    float bv[4];
    #pragma unroll
    for (int n = 0; n < 4; ++n)
        bv[n] = bias[bn + wc * 64 + n * 16 + lr];

    #pragma unroll
    for (int m = 0; m < 4; ++m) {
        #pragma unroll
        for (int r = 0; r < 4; ++r) {
            const int row = bm + wr * 64 + m * 16 + g * 4 + r;
            float amax = 0.f;
            #pragma unroll
            for (int n = 0; n < 4; ++n) {
                const float v = acc[m][n][r] + bv[n];
                out[(size_t)row * N + (bn + wc * 64 + n * 16 + lr)] = v;
                amax = fmaxf(amax, fabsf(v));
            }
            #pragma unroll
            for (int off = 1; off < 16; off <<= 1)
                amax = fmaxf(amax, __shfl_xor(amax, off));
            if (lr == 0)
                atomicMax(rowmax + row, __float_as_int(amax));
        }
    }
}

// ---------------- quantize + ReLU ----------------
__global__ __launch_bounds__(256) void quant_relu(
    float* __restrict__ y, const int* __restrict__ rowmax)
{
    const int nvec = (M * N) / 4;   // 1024 float4 per row
    for (int i = blockIdx.x * blockDim.x + threadIdx.x; i < nvec;
         i += gridDim.x * blockDim.x) {
        const int row = i >> 10;
        const float mx = __int_as_float(rowmax[row]);
        f32x4 v = ((const f32x4*)y)[i];
        if (mx > 0.f) {
            const int e = ilogbf(mx);                 // floor(log2(mx))
            const float step = ldexpf(1.0f, e - 6);   // 2^(e + 2 - wl), wl=8
            const float inv  = ldexpf(1.0f, 6 - e);   // exact pow2 reciprocal
            #pragma unroll
            for (int j = 0; j < 4; ++j)
                v[j] = floorf(v[j] * inv + 0.5f) * step;
        }
        #pragma unroll
        for (int j = 0; j < 4; ++j)
            v[j] = fmaxf(v[j], 0.f);
        ((f32x4*)y)[i] = v;
    }
}

extern "C" void kernel_launch(void* const* d_in, const int* in_sizes, int n_in,
                              void* d_out, int out_size, void* d_ws, size_t ws_size,
                              hipStream_t stream) {
    const float* x = (const float*)d_in[0];
    const float* w = (const float*)d_in[1];
    const float* b = (const float*)d_in[2];
    float* out = (float*)d_out;

    const size_t XB  = (size_t)M * K * 2;   // x in bf16: 64 MiB
    const size_t WB  = (size_t)N * K * 2;   // W in bf16: 32 MiB
    const size_t REQ = XB + WB + (size_t)M * 4;

    if (ws_size >= REQ) {
        unsigned short* xb = (unsigned short*)d_ws;
        unsigned short* wb = (unsigned short*)((char*)d_ws + XB);
        int* rowmax        = (int*)((char*)d_ws + XB + WB);

        hipMemsetAsync(rowmax, 0, M * sizeof(int), stream);
        cvt_bf16<<<2048, 256, 0, stream>>>(x, xb, (M * K) / 8);
        cvt_bf16<<<1024, 256, 0, stream>>>(w, wb, (N * K) / 8);
        gemm_bf16<<<dim3((M / BM) * (N / BN)), 256, 0, stream>>>(xb, wb, b, out, rowmax);
        quant_relu<<<2048, 256, 0, stream>>>(out, rowmax);
    } else {
        int* rowmax = (int*)d_ws;
        hipMemsetAsync(rowmax, 0, M * sizeof(int), stream);
        gemm_rowmax<<<dim3((M / BM) * (N / BN)), 256, 0, stream>>>(x, w, b, out, rowmax);
        quant_relu<<<2048, 256, 0, stream>>>(out, rowmax);
    }
}

// Round 5
// 545.986 us; speedup vs baseline: 1.6169x; 1.2620x over previous
//
#include <hip/hip_runtime.h>

#define M 8192
#define N 4096
#define K 4096
#define BM 256
#define BN 256
#define BK 64
#define NKT (K / BK)     // 64 K-tiles
#define NIT (NKT / 2)    // 32 main-loop iterations (2 K-tiles each)

typedef __attribute__((ext_vector_type(8))) short bf16x8;
typedef __attribute__((ext_vector_type(4))) float f32x4;
typedef __attribute__((address_space(1))) const unsigned GU;
typedef __attribute__((address_space(3))) unsigned LU;

__device__ __forceinline__ unsigned short f2bf(float f) {
    unsigned u = __float_as_uint(f);
    u += 0x7fffu + ((u >> 16) & 1u);   // round-to-nearest-even
    return (unsigned short)(u >> 16);
}

// ---------------- fp32 -> bf16 convert ----------------
__global__ __launch_bounds__(256) void cvt_bf16(const float* __restrict__ src,
                                                unsigned short* __restrict__ dst,
                                                int n8) {
    const int stride = gridDim.x * blockDim.x;
    for (int i = blockIdx.x * blockDim.x + threadIdx.x; i < n8; i += stride) {
        f32x4 a = ((const f32x4*)src)[2 * i];
        f32x4 b = ((const f32x4*)src)[2 * i + 1];
        bf16x8 v;
        #pragma unroll
        for (int j = 0; j < 4; ++j) {
            v[j]     = (short)f2bf(a[j]);
            v[4 + j] = (short)f2bf(b[j]);
        }
        ((bf16x8*)dst)[i] = v;
    }
}

// ---------------- 256x256 8-phase bf16 GEMM (T2+T3+T4+T5) ----------------
#define BAR()   __builtin_amdgcn_s_barrier()
#define LGKM0() do { asm volatile("s_waitcnt lgkmcnt(0)" ::: "memory"); \
                     __builtin_amdgcn_sched_barrier(0); } while (0)
#define LGKM8() asm volatile("s_waitcnt lgkmcnt(8)" ::: "memory")
#define VM6()   asm volatile("s_waitcnt vmcnt(6)" ::: "memory")

// one 16-MFMA quadrant (4m x 2n x 2ks), setprio-wrapped (T5)
#define QUAD(AR, BR, MOFF, NOFF)                                               \
    do {                                                                       \
        __builtin_amdgcn_s_setprio(1);                                         \
        _Pragma("unroll")                                                      \
        for (int m_ = 0; m_ < 4; ++m_) {                                       \
            _Pragma("unroll")                                                  \
            for (int n_ = 0; n_ < 2; ++n_) {                                   \
                acc[MOFF + m_][NOFF + n_] =                                    \
                    __builtin_amdgcn_mfma_f32_16x16x32_bf16(                   \
                        AR[m_][0], BR[n_][0], acc[MOFF + m_][NOFF + n_], 0, 0, 0); \
                acc[MOFF + m_][NOFF + n_] =                                    \
                    __builtin_amdgcn_mfma_f32_16x16x32_bf16(                   \
                        AR[m_][1], BR[n_][1], acc[MOFF + m_][NOFF + n_], 0, 0, 0); \
            }                                                                  \
        }                                                                      \
        __builtin_amdgcn_s_setprio(0);                                         \
    } while (0)

__global__ __launch_bounds__(512, 2) void gemm_bf16(
    const unsigned short* __restrict__ xb, const unsigned short* __restrict__ wb,
    const float* __restrict__ bias, float* __restrict__ out,
    int* __restrict__ rowmax)
{
    // per K-tile buffer: 2 halves x 16 subtiles(1024B: 16 rows x 32 cols bf16)
    __shared__ short As[2][16384];   // 2 x 32 KB
    __shared__ short Bs[2][16384];   // 2 x 32 KB   (total 128 KiB)

    const int bid = blockIdx.x;
    const int tm = bid % (M / BM);
    const int tn = bid / (M / BM);
    const int bm = tm * BM, bn = tn * BN;

    const int t    = threadIdx.x;     // 0..511
    const int w_id = t >> 6;          // wave 0..7
    const int l    = t & 63;
    const int wr   = w_id >> 2;       // 0..1 : A half (128 rows)
    const int wc   = w_id & 3;        // 0..3 : 64-col B slice
    const int lr   = l & 15;
    const int g    = l >> 4;

    // staging lane constants (inverse st_16x32 swizzle on the GLOBAL source)
    const int srow_l = l >> 2;                            // row in subtile
    const int scol_l = ((l & 3) * 8) ^ ((l >> 5) * 16);   // col elems in subtile
    // read lane offset within a subtile (shorts), swizzled
    const int loff = lr * 32 + ((g * 8) ^ ((lr >> 3) << 4));

    auto stageA = [&](int buf, int h, int kt) {
        #pragma unroll
        for (int j = 0; j < 2; ++j) {
            const int s = w_id * 2 + j;
            const unsigned short* gp =
                xb + (size_t)(bm + h * 128 + (s >> 1) * 16 + srow_l) * K
                   + kt * 64 + (s & 1) * 32 + scol_l;
            __builtin_amdgcn_global_load_lds(
                (const GU*)gp, (LU*)&As[buf][h * 8192 + s * 512], 16, 0, 0);
        }
    };
    auto stageB = [&](int buf, int h, int kt) {
        #pragma unroll
        for (int j = 0; j < 2; ++j) {
            const int s = w_id * 2 + j;
            const unsigned short* gp =
                wb + (size_t)(bn + h * 128 + (s >> 1) * 16 + srow_l) * K
                   + kt * 64 + (s & 1) * 32 + scol_l;
            __builtin_amdgcn_global_load_lds(
                (const GU*)gp, (LU*)&Bs[buf][h * 8192 + s * 512], 16, 0, 0);
        }
    };
    auto ldA = [&](int buf, int m, int ks) -> bf16x8 {
        return *(const bf16x8*)&As[buf][wr * 8192 + (m * 2 + ks) * 512 + loff];
    };
    auto ldB = [&](int buf, int n, int ks) -> bf16x8 {   // n = 0..3 (full index)
        return *(const bf16x8*)&Bs[buf][(wc >> 1) * 8192 +
                                        (((wc & 1) * 4 + n) * 2 + ks) * 512 + loff];
    };

    f32x4 acc[8][4];
    #pragma unroll
    for (int m = 0; m < 8; ++m)
        #pragma unroll
        for (int n = 0; n < 4; ++n)
            acc[m][n] = (f32x4){0.f, 0.f, 0.f, 0.f};

    bf16x8 a03[4][2], a47[4][2], b01[2][2], b23[2][2];

    // prologue: tile0 (4 half-tiles, buf0) + tile1 (3 half-tiles, buf1)
    stageB(0, 0, 0); stageB(0, 1, 0); stageA(0, 0, 0); stageA(0, 1, 0);
    stageB(1, 0, 1); stageB(1, 1, 1); stageA(1, 0, 1);
    VM6();   // tile0's 8 loads retired; tile1's 6 may be in flight
    BAR();

    for (int it = 0; it < NIT; ++it) {
        const int t1  = 2 * it + 1;
        const int tp0 = (2 * it + 2) & (NKT - 1);   // wraps harmlessly on last iter
        const int tp1 = (2 * it + 3) & (NKT - 1);

        // ======== K-tile 2it from buf0 ========
        // ph1: read A0-3 + B0-1; stage A-half1 of tile 2it+1 -> buf1
        #pragma unroll
        for (int m = 0; m < 4; ++m) { a03[m][0] = ldA(0, m, 0); a03[m][1] = ldA(0, m, 1); }
        #pragma unroll
        for (int n = 0; n < 2; ++n) { b01[n][0] = ldB(0, n, 0); b01[n][1] = ldB(0, n, 1); }
        stageA(1, 1, t1);
        LGKM8();
        BAR(); LGKM0();
        QUAD(a03, b01, 0, 0);
        BAR();

        // ph2: read B2-3; stage B-half0 of tile 2it+2 -> buf0
        #pragma unroll
        for (int n = 0; n < 2; ++n) { b23[n][0] = ldB(0, 2 + n, 0); b23[n][1] = ldB(0, 2 + n, 1); }
        stageB(0, 0, tp0);
        BAR(); LGKM0();
        QUAD(a03, b23, 0, 2);
        BAR();

        // ph3: read A4-7; stage B-half1 -> buf0
        #pragma unroll
        for (int m = 0; m < 4; ++m) { a47[m][0] = ldA(0, 4 + m, 0); a47[m][1] = ldA(0, 4 + m, 1); }
        stageB(0, 1, tp0);
        BAR(); LGKM0();
        QUAD(a47, b23, 4, 2);
        BAR();

        // ph4: no reads (reuse a47,b01); stage A-half0 -> buf0; vmcnt gate
        stageA(0, 0, tp0);
        BAR(); LGKM0();
        QUAD(a47, b01, 4, 0);
        VM6();
        BAR();

        // ======== K-tile 2it+1 from buf1 ========
        // ph5: read A0-3 + B0-1; stage A-half1 of tile 2it+2 -> buf0
        #pragma unroll
        for (int m = 0; m < 4; ++m) { a03[m][0] = ldA(1, m, 0); a03[m][1] = ldA(1, m, 1); }
        #pragma unroll
        for (int n = 0; n < 2; ++n) { b01[n][0] = ldB(1, n, 0); b01[n][1] = ldB(1, n, 1); }
        stageA(0, 1, tp0);
        LGKM8();
        BAR(); LGKM0();
        QUAD(a03, b01, 0, 0);
        BAR();

        // ph6: read B2-3; stage B-half0 of tile 2it+3 -> buf1
        #pragma unroll
        for (int n = 0; n < 2; ++n) { b23[n][0] = ldB(1, 2 + n, 0); b23[n][1] = ldB(1, 2 + n, 1); }
        stageB(1, 0, tp1);
        BAR(); LGKM0();
        QUAD(a03, b23, 0, 2);
        BAR();

        // ph7: read A4-7; stage B-half1 -> buf1
        #pragma unroll
        for (int m = 0; m < 4; ++m) { a47[m][0] = ldA(1, 4 + m, 0); a47[m][1] = ldA(1, 4 + m, 1); }
        stageB(1, 1, tp1);
        BAR(); LGKM0();
        QUAD(a47, b23, 4, 2);
        BAR();

        // ph8: no reads; stage A-half0 -> buf1; vmcnt gate
        stageA(1, 0, tp1);
        BAR(); LGKM0();
        QUAD(a47, b01, 4, 0);
        VM6();
        BAR();
    }

    // epilogue: bias, store h, per-row |max| -> atomicMax
    float bv[4];
    #pragma unroll
    for (int n = 0; n < 4; ++n)
        bv[n] = bias[bn + wc * 64 + n * 16 + lr];

    #pragma unroll
    for (int m = 0; m < 8; ++m) {
        #pragma unroll
        for (int r = 0; r < 4; ++r) {
            const int row = bm + wr * 128 + m * 16 + g * 4 + r;
            float amax = 0.f;
            #pragma unroll
            for (int n = 0; n < 4; ++n) {
                const float v = acc[m][n][r] + bv[n];
                out[(size_t)row * N + (bn + wc * 64 + n * 16 + lr)] = v;
                amax = fmaxf(amax, fabsf(v));
            }
            #pragma unroll
            for (int off = 1; off < 16; off <<= 1)
                amax = fmaxf(amax, __shfl_xor(amax, off));
            if (lr == 0)
                atomicMax(rowmax + row, __float_as_int(amax));
        }
    }
}

// ---------------- quantize + ReLU ----------------
__global__ __launch_bounds__(256) void quant_relu(
    float* __restrict__ y, const int* __restrict__ rowmax)
{
    const int nvec = (M * N) / 4;   // 1024 float4 per row
    for (int i = blockIdx.x * blockDim.x + threadIdx.x; i < nvec;
         i += gridDim.x * blockDim.x) {
        const int row = i >> 10;
        const float mx = __int_as_float(rowmax[row]);
        f32x4 v = ((const f32x4*)y)[i];
        if (mx > 0.f) {
            const int e = ilogbf(mx);                 // floor(log2(mx))
            const float step = ldexpf(1.0f, e - 6);   // 2^(e + 2 - wl), wl=8
            const float inv  = ldexpf(1.0f, 6 - e);   // exact pow2 reciprocal
            #pragma unroll
            for (int j = 0; j < 4; ++j)
                v[j] = floorf(v[j] * inv + 0.5f) * step;
        }
        #pragma unroll
        for (int j = 0; j < 4; ++j)
            v[j] = fmaxf(v[j], 0.f);
        ((f32x4*)y)[i] = v;
    }
}

extern "C" void kernel_launch(void* const* d_in, const int* in_sizes, int n_in,
                              void* d_out, int out_size, void* d_ws, size_t ws_size,
                              hipStream_t stream) {
    const float* x = (const float*)d_in[0];
    const float* w = (const float*)d_in[1];
    const float* b = (const float*)d_in[2];
    float* out = (float*)d_out;

    const size_t XB = (size_t)M * K * 2;   // 64 MiB
    const size_t WB = (size_t)N * K * 2;   // 32 MiB

    unsigned short* xb = (unsigned short*)d_ws;
    unsigned short* wb = (unsigned short*)((char*)d_ws + XB);
    int* rowmax        = (int*)((char*)d_ws + XB + WB);

    hipMemsetAsync(rowmax, 0, M * sizeof(int), stream);
    cvt_bf16<<<2048, 256, 0, stream>>>(x, xb, (M * K) / 8);
    cvt_bf16<<<1024, 256, 0, stream>>>(w, wb, (N * K) / 8);
    gemm_bf16<<<dim3((M / BM) * (N / BN)), 512, 0, stream>>>(xb, wb, b, out, rowmax);
    quant_relu<<<2048, 256, 0, stream>>>(out, rowmax);
}

// Round 6
// 534.910 us; speedup vs baseline: 1.6503x; 1.0207x over previous
//
#include <hip/hip_runtime.h>

#define M 8192
#define N 4096
#define K 4096
#define BM 256
#define BN 256
#define BK 64
#define NKT (K / BK)     // 64 K-tiles
#define NIT (NKT / 2)    // 32 main-loop iterations (2 K-tiles each)

typedef __attribute__((ext_vector_type(8))) short bf16x8;
typedef __attribute__((ext_vector_type(4))) short bf16x4;
typedef __attribute__((ext_vector_type(4))) float f32x4;
typedef __attribute__((address_space(1))) const unsigned GU;
typedef __attribute__((address_space(3))) unsigned LU;

__device__ __forceinline__ unsigned short f2bf(float f) {
    unsigned u = __float_as_uint(f);
    u += 0x7fffu + ((u >> 16) & 1u);   // round-to-nearest-even
    return (unsigned short)(u >> 16);
}

// ------- fused fp32 -> bf16 convert for x and W (unit-stride f32x4 loads) -------
__global__ __launch_bounds__(256) void cvt_bf16_2(
    const float* __restrict__ s1, unsigned short* __restrict__ d1, int n1_4,
    const float* __restrict__ s2, unsigned short* __restrict__ d2, int n2_4)
{
    const int stride = gridDim.x * blockDim.x;
    const int total = n1_4 + n2_4;
    for (int i = blockIdx.x * blockDim.x + threadIdx.x; i < total; i += stride) {
        const float* s;
        unsigned short* d;
        int j;
        if (i < n1_4) { s = s1; d = d1; j = i; }
        else          { s = s2; d = d2; j = i - n1_4; }
        f32x4 v = ((const f32x4*)s)[j];
        bf16x4 o;
        #pragma unroll
        for (int k = 0; k < 4; ++k) o[k] = (short)f2bf(v[k]);
        ((bf16x4*)d)[j] = o;
    }
}

// ---------------- 256x256 8-phase bf16 GEMM (T2+T3+T4+T5) ----------------
#define BAR()   __builtin_amdgcn_s_barrier()
#define LGKM0() do { asm volatile("s_waitcnt lgkmcnt(0)" ::: "memory"); \
                     __builtin_amdgcn_sched_barrier(0); } while (0)
#define LGKM8() asm volatile("s_waitcnt lgkmcnt(8)" ::: "memory")
#define VM6()   asm volatile("s_waitcnt vmcnt(6)" ::: "memory")

// one 16-MFMA quadrant (4m x 2n x 2ks), setprio-wrapped (T5)
#define QUAD(AR, BR, MOFF, NOFF)                                               \
    do {                                                                       \
        __builtin_amdgcn_s_setprio(1);                                         \
        _Pragma("unroll")                                                      \
        for (int m_ = 0; m_ < 4; ++m_) {                                       \
            _Pragma("unroll")                                                  \
            for (int n_ = 0; n_ < 2; ++n_) {                                   \
                acc[MOFF + m_][NOFF + n_] =                                    \
                    __builtin_amdgcn_mfma_f32_16x16x32_bf16(                   \
                        AR[m_][0], BR[n_][0], acc[MOFF + m_][NOFF + n_], 0, 0, 0); \
                acc[MOFF + m_][NOFF + n_] =                                    \
                    __builtin_amdgcn_mfma_f32_16x16x32_bf16(                   \
                        AR[m_][1], BR[n_][1], acc[MOFF + m_][NOFF + n_], 0, 0, 0); \
            }                                                                  \
        }                                                                      \
        __builtin_amdgcn_s_setprio(0);                                         \
    } while (0)

__global__ __launch_bounds__(512, 2) void gemm_bf16(
    const unsigned short* __restrict__ xb, const unsigned short* __restrict__ wb,
    const float* __restrict__ bias, float* __restrict__ out,
    int* __restrict__ rowmax)
{
    // single 128-KiB LDS pool:
    //   main loop: A dbuf = smem[0..32767], B dbuf = smem[32768..65535]
    //   epilogue : reused as float[128][256] transpose buffer
    __shared__ __align__(16) short smem[65536];

    const int bid = blockIdx.x;
    const int tm = bid % (M / BM);
    const int tn = bid / (M / BM);
    const int bm = tm * BM, bn = tn * BN;

    const int t    = threadIdx.x;     // 0..511
    const int w_id = t >> 6;          // wave 0..7
    const int l    = t & 63;
    const int wr   = w_id >> 2;       // 0..1 : A half (128 rows)
    const int wc   = w_id & 3;        // 0..3 : 64-col B slice
    const int lr   = l & 15;
    const int g    = l >> 4;

    // staging lane constants (inverse st_16x32 swizzle on the GLOBAL source)
    const int srow_l = l >> 2;                            // row in subtile
    const int scol_l = ((l & 3) * 8) ^ ((l >> 5) * 16);   // col elems in subtile
    // read lane offset within a subtile (shorts), swizzled
    const int loff = lr * 32 + ((g * 8) ^ ((lr >> 3) << 4));

    auto stageA = [&](int buf, int h, int kt) {
        #pragma unroll
        for (int j = 0; j < 2; ++j) {
            const int s = w_id * 2 + j;
            const unsigned short* gp =
                xb + (size_t)(bm + h * 128 + (s >> 1) * 16 + srow_l) * K
                   + kt * 64 + (s & 1) * 32 + scol_l;
            __builtin_amdgcn_global_load_lds(
                (const GU*)gp, (LU*)&smem[buf * 16384 + h * 8192 + s * 512], 16, 0, 0);
        }
    };
    auto stageB = [&](int buf, int h, int kt) {
        #pragma unroll
        for (int j = 0; j < 2; ++j) {
            const int s = w_id * 2 + j;
            const unsigned short* gp =
                wb + (size_t)(bn + h * 128 + (s >> 1) * 16 + srow_l) * K
                   + kt * 64 + (s & 1) * 32 + scol_l;
            __builtin_amdgcn_global_load_lds(
                (const GU*)gp, (LU*)&smem[32768 + buf * 16384 + h * 8192 + s * 512], 16, 0, 0);
        }
    };
    auto ldA = [&](int buf, int m, int ks) -> bf16x8 {
        return *(const bf16x8*)&smem[buf * 16384 + wr * 8192 + (m * 2 + ks) * 512 + loff];
    };
    auto ldB = [&](int buf, int n, int ks) -> bf16x8 {   // n = 0..3 (full index)
        return *(const bf16x8*)&smem[32768 + buf * 16384 + (wc >> 1) * 8192 +
                                     (((wc & 1) * 4 + n) * 2 + ks) * 512 + loff];
    };

    f32x4 acc[8][4];
    #pragma unroll
    for (int m = 0; m < 8; ++m)
        #pragma unroll
        for (int n = 0; n < 4; ++n)
            acc[m][n] = (f32x4){0.f, 0.f, 0.f, 0.f};

    bf16x8 a03[4][2], a47[4][2], b01[2][2], b23[2][2];

    // prologue: tile0 (4 half-tiles, buf0) + tile1 (3 half-tiles, buf1)
    stageB(0, 0, 0); stageB(0, 1, 0); stageA(0, 0, 0); stageA(0, 1, 0);
    stageB(1, 0, 1); stageB(1, 1, 1); stageA(1, 0, 1);
    VM6();   // tile0's 8 loads retired; tile1's 6 may be in flight
    BAR();

    for (int it = 0; it < NIT; ++it) {
        const int t1  = 2 * it + 1;
        const int tp0 = (2 * it + 2) & (NKT - 1);   // wraps harmlessly on last iter
        const int tp1 = (2 * it + 3) & (NKT - 1);

        // ======== K-tile 2it from buf0 ========
        // ph1: read A0-3 + B0-1; stage A-half1 of tile 2it+1 -> buf1
        #pragma unroll
        for (int m = 0; m < 4; ++m) { a03[m][0] = ldA(0, m, 0); a03[m][1] = ldA(0, m, 1); }
        #pragma unroll
        for (int n = 0; n < 2; ++n) { b01[n][0] = ldB(0, n, 0); b01[n][1] = ldB(0, n, 1); }
        stageA(1, 1, t1);
        LGKM8();
        BAR(); LGKM0();
        QUAD(a03, b01, 0, 0);
        BAR();

        // ph2: read B2-3; stage B-half0 of tile 2it+2 -> buf0
        #pragma unroll
        for (int n = 0; n < 2; ++n) { b23[n][0] = ldB(0, 2 + n, 0); b23[n][1] = ldB(0, 2 + n, 1); }
        stageB(0, 0, tp0);
        BAR(); LGKM0();
        QUAD(a03, b23, 0, 2);
        BAR();

        // ph3: read A4-7; stage B-half1 -> buf0
        #pragma unroll
        for (int m = 0; m < 4; ++m) { a47[m][0] = ldA(0, 4 + m, 0); a47[m][1] = ldA(0, 4 + m, 1); }
        stageB(0, 1, tp0);
        BAR(); LGKM0();
        QUAD(a47, b23, 4, 2);
        BAR();

        // ph4: no reads (reuse a47,b01); stage A-half0 -> buf0; vmcnt gate
        stageA(0, 0, tp0);
        BAR(); LGKM0();
        QUAD(a47, b01, 4, 0);
        VM6();
        BAR();

        // ======== K-tile 2it+1 from buf1 ========
        // ph5: read A0-3 + B0-1; stage A-half1 of tile 2it+2 -> buf0
        #pragma unroll
        for (int m = 0; m < 4; ++m) { a03[m][0] = ldA(1, m, 0); a03[m][1] = ldA(1, m, 1); }
        #pragma unroll
        for (int n = 0; n < 2; ++n) { b01[n][0] = ldB(1, n, 0); b01[n][1] = ldB(1, n, 1); }
        stageA(0, 1, tp0);
        LGKM8();
        BAR(); LGKM0();
        QUAD(a03, b01, 0, 0);
        BAR();

        // ph6: read B2-3; stage B-half0 of tile 2it+3 -> buf1
        #pragma unroll
        for (int n = 0; n < 2; ++n) { b23[n][0] = ldB(1, 2 + n, 0); b23[n][1] = ldB(1, 2 + n, 1); }
        stageB(1, 0, tp1);
        BAR(); LGKM0();
        QUAD(a03, b23, 0, 2);
        BAR();

        // ph7: read A4-7; stage B-half1 -> buf1
        #pragma unroll
        for (int m = 0; m < 4; ++m) { a47[m][0] = ldA(1, 4 + m, 0); a47[m][1] = ldA(1, 4 + m, 1); }
        stageB(1, 1, tp1);
        BAR(); LGKM0();
        QUAD(a47, b23, 4, 2);
        BAR();

        // ph8: no reads; stage A-half0 -> buf1; vmcnt gate
        stageA(1, 0, tp1);
        BAR(); LGKM0();
        QUAD(a47, b01, 4, 0);
        VM6();
        BAR();
    }

    __syncthreads();   // all LDS reads of the main loop done; smem free for reuse

    // ---- epilogue part 1: fold bias into acc, per-row |max| -> atomicMax ----
    float bv[4];
    #pragma unroll
    for (int n = 0; n < 4; ++n)
        bv[n] = bias[bn + wc * 64 + n * 16 + lr];

    #pragma unroll
    for (int m = 0; m < 8; ++m) {
        #pragma unroll
        for (int r = 0; r < 4; ++r) {
            const int row = bm + wr * 128 + m * 16 + g * 4 + r;
            float amax = 0.f;
            #pragma unroll
            for (int n = 0; n < 4; ++n) {
                acc[m][n][r] += bv[n];                 // same FP op order as before
                amax = fmaxf(amax, fabsf(acc[m][n][r]));
            }
            #pragma unroll
            for (int off = 1; off < 16; off <<= 1)
                amax = fmaxf(amax, __shfl_xor(amax, off));
            if (lr == 0)
                atomicMax(rowmax + row, __float_as_int(amax));
        }
    }

    // ---- epilogue part 2: LDS-transposed, coalesced fp32 h store ----
    // two passes of 128 rows; LDS as float[128][256] (128 KiB)
    float* hs = (float*)smem;
    #pragma unroll
    for (int p = 0; p < 2; ++p) {
        if (p) __syncthreads();                        // protect pass-0 reads
        if (wr == p) {
            #pragma unroll
            for (int m = 0; m < 8; ++m)
                #pragma unroll
                for (int r = 0; r < 4; ++r)
                    #pragma unroll
                    for (int n = 0; n < 4; ++n)
                        hs[(m * 16 + g * 4 + r) * 256 + wc * 64 + n * 16 + lr] =
                            acc[m][n][r];
        }
        __syncthreads();
        // 128 rows x 1 KiB: 512 threads x f32x4 x 16 iters, wave = one full row
        #pragma unroll
        for (int j = 0; j < 16; ++j) {
            const int fi  = j * 2048 + t * 4;          // float index in [128][256]
            const int row = fi >> 8;
            const int col = fi & 255;
            *(f32x4*)&out[(size_t)(bm + p * 128 + row) * N + bn + col] =
                *(const f32x4*)&hs[fi];
        }
    }
}

// ---------------- quantize + ReLU (in-place on out) ----------------
__global__ __launch_bounds__(256) void quant_relu(
    float* __restrict__ y, const int* __restrict__ rowmax)
{
    const int nvec = (M * N) / 4;   // 1024 float4 per row
    for (int i = blockIdx.x * blockDim.x + threadIdx.x; i < nvec;
         i += gridDim.x * blockDim.x) {
        const int row = i >> 10;
        const float mx = __int_as_float(rowmax[row]);
        f32x4 v = ((const f32x4*)y)[i];
        if (mx > 0.f) {
            const int e = ilogbf(mx);                 // floor(log2(mx))
            const float step = ldexpf(1.0f, e - 6);   // 2^(e + 2 - wl), wl=8
            const float inv  = ldexpf(1.0f, 6 - e);   // exact pow2 reciprocal
            #pragma unroll
            for (int j = 0; j < 4; ++j)
                v[j] = floorf(v[j] * inv + 0.5f) * step;
        }
        #pragma unroll
        for (int j = 0; j < 4; ++j)
            v[j] = fmaxf(v[j], 0.f);
        ((f32x4*)y)[i] = v;
    }
}

extern "C" void kernel_launch(void* const* d_in, const int* in_sizes, int n_in,
                              void* d_out, int out_size, void* d_ws, size_t ws_size,
                              hipStream_t stream) {
    const float* x = (const float*)d_in[0];
    const float* w = (const float*)d_in[1];
    const float* b = (const float*)d_in[2];
    float* out = (float*)d_out;

    const size_t XB = (size_t)M * K * 2;   // 64 MiB
    const size_t WB = (size_t)N * K * 2;   // 32 MiB

    unsigned short* xb = (unsigned short*)d_ws;
    unsigned short* wb = (unsigned short*)((char*)d_ws + XB);
    int* rowmax        = (int*)((char*)d_ws + XB + WB);

    hipMemsetAsync(rowmax, 0, M * sizeof(int), stream);
    cvt_bf16_2<<<3072, 256, 0, stream>>>(x, xb, (M * K) / 4, w, wb, (N * K) / 4);
    gemm_bf16<<<dim3((M / BM) * (N / BN)), 512, 0, stream>>>(xb, wb, b, out, rowmax);
    quant_relu<<<2048, 256, 0, stream>>>(out, rowmax);
}

// Round 7
// 532.210 us; speedup vs baseline: 1.6587x; 1.0051x over previous
//
#include <hip/hip_runtime.h>

#define M 8192
#define N 4096
#define K 4096
#define BM 256
#define BN 256
#define BK 64
#define NKT (K / BK)     // 64 K-tiles
#define NIT (NKT / 2)    // 32 main-loop iterations (2 K-tiles each)

typedef __attribute__((ext_vector_type(8))) short bf16x8;
typedef __attribute__((ext_vector_type(4))) short bf16x4;
typedef __attribute__((ext_vector_type(4))) float f32x4;
typedef __attribute__((address_space(1))) const unsigned GU;
typedef __attribute__((address_space(3))) unsigned LU;

__device__ __forceinline__ unsigned short f2bf(float f) {
    unsigned u = __float_as_uint(f);
    u += 0x7fffu + ((u >> 16) & 1u);   // round-to-nearest-even
    return (unsigned short)(u >> 16);
}

// ------- fused fp32->bf16 convert for x and W, 4-deep MLP; also zeroes rowmax -------
// total (n1_4+n2_4) must be a multiple of 16*gridDim*blockDim (holds: 12.58M = 16*786432)
__global__ __launch_bounds__(256) void cvt_bf16_2(
    const float* __restrict__ s1, unsigned short* __restrict__ d1, int n1_4,
    const float* __restrict__ s2, unsigned short* __restrict__ d2, int n2_4,
    int* __restrict__ rowmax)
{
    if (blockIdx.x < 32) rowmax[(blockIdx.x << 8) | threadIdx.x] = 0;   // 8192 ints

    const int span = gridDim.x * blockDim.x;
    const int tid  = blockIdx.x * blockDim.x + threadIdx.x;
    const int total = n1_4 + n2_4;

    for (int base = tid; base < total; base += 4 * span) {
        f32x4 v[4];
        #pragma unroll
        for (int j = 0; j < 4; ++j) {              // 4 independent loads in flight
            const int i = base + j * span;
            const f32x4* p = (i < n1_4) ? ((const f32x4*)s1) + i
                                        : ((const f32x4*)s2) + (i - n1_4);
            v[j] = *p;
        }
        #pragma unroll
        for (int j = 0; j < 4; ++j) {
            const int i = base + j * span;
            bf16x4 o;
            #pragma unroll
            for (int k = 0; k < 4; ++k) o[k] = (short)f2bf(v[j][k]);
            bf16x4* q = (i < n1_4) ? ((bf16x4*)d1) + i : ((bf16x4*)d2) + (i - n1_4);
            *q = o;
        }
    }
}

// ---------------- 256x256 8-phase bf16 GEMM (T2+T3+T4+T5) ----------------
#define BAR()   __builtin_amdgcn_s_barrier()
#define LGKM0() do { asm volatile("s_waitcnt lgkmcnt(0)" ::: "memory"); \
                     __builtin_amdgcn_sched_barrier(0); } while (0)
#define LGKM8() asm volatile("s_waitcnt lgkmcnt(8)" ::: "memory")
#define VM6()   asm volatile("s_waitcnt vmcnt(6)" ::: "memory")

// one 16-MFMA quadrant (4m x 2n x 2ks), setprio-wrapped (T5)
#define QUAD(AR, BR, MOFF, NOFF)                                               \
    do {                                                                       \
        __builtin_amdgcn_s_setprio(1);                                         \
        _Pragma("unroll")                                                      \
        for (int m_ = 0; m_ < 4; ++m_) {                                       \
            _Pragma("unroll")                                                  \
            for (int n_ = 0; n_ < 2; ++n_) {                                   \
                acc[MOFF + m_][NOFF + n_] =                                    \
                    __builtin_amdgcn_mfma_f32_16x16x32_bf16(                   \
                        AR[m_][0], BR[n_][0], acc[MOFF + m_][NOFF + n_], 0, 0, 0); \
                acc[MOFF + m_][NOFF + n_] =                                    \
                    __builtin_amdgcn_mfma_f32_16x16x32_bf16(                   \
                        AR[m_][1], BR[n_][1], acc[MOFF + m_][NOFF + n_], 0, 0, 0); \
            }                                                                  \
        }                                                                      \
        __builtin_amdgcn_s_setprio(0);                                         \
    } while (0)

__global__ __launch_bounds__(512, 2) void gemm_bf16(
    const unsigned short* __restrict__ xb, const unsigned short* __restrict__ wb,
    const float* __restrict__ bias, float* __restrict__ out,
    int* __restrict__ rowmax)
{
    // single 128-KiB LDS pool:
    //   main loop: A dbuf = smem[0..32767], B dbuf = smem[32768..65535]
    //   epilogue : reused as float[128][256] transpose buffer
    __shared__ __align__(16) short smem[65536];

    const int bid = blockIdx.x;
    const int tm = bid % (M / BM);
    const int tn = bid / (M / BM);
    const int bm = tm * BM, bn = tn * BN;

    const int t    = threadIdx.x;     // 0..511
    const int w_id = t >> 6;          // wave 0..7
    const int l    = t & 63;
    const int wr   = w_id >> 2;       // 0..1 : A half (128 rows)
    const int wc   = w_id & 3;        // 0..3 : 64-col B slice
    const int lr   = l & 15;
    const int g    = l >> 4;

    // staging lane constants (inverse st_16x32 swizzle on the GLOBAL source)
    const int srow_l = l >> 2;                            // row in subtile
    const int scol_l = ((l & 3) * 8) ^ ((l >> 5) * 16);   // col elems in subtile
    // read lane offset within a subtile (shorts), swizzled
    const int loff = lr * 32 + ((g * 8) ^ ((lr >> 3) << 4));

    auto stageA = [&](int buf, int h, int kt) {
        #pragma unroll
        for (int j = 0; j < 2; ++j) {
            const int s = w_id * 2 + j;
            const unsigned short* gp =
                xb + (size_t)(bm + h * 128 + (s >> 1) * 16 + srow_l) * K
                   + kt * 64 + (s & 1) * 32 + scol_l;
            __builtin_amdgcn_global_load_lds(
                (const GU*)gp, (LU*)&smem[buf * 16384 + h * 8192 + s * 512], 16, 0, 0);
        }
    };
    auto stageB = [&](int buf, int h, int kt) {
        #pragma unroll
        for (int j = 0; j < 2; ++j) {
            const int s = w_id * 2 + j;
            const unsigned short* gp =
                wb + (size_t)(bn + h * 128 + (s >> 1) * 16 + srow_l) * K
                   + kt * 64 + (s & 1) * 32 + scol_l;
            __builtin_amdgcn_global_load_lds(
                (const GU*)gp, (LU*)&smem[32768 + buf * 16384 + h * 8192 + s * 512], 16, 0, 0);
        }
    };
    auto ldA = [&](int buf, int m, int ks) -> bf16x8 {
        return *(const bf16x8*)&smem[buf * 16384 + wr * 8192 + (m * 2 + ks) * 512 + loff];
    };
    auto ldB = [&](int buf, int n, int ks) -> bf16x8 {   // n = 0..3 (full index)
        return *(const bf16x8*)&smem[32768 + buf * 16384 + (wc >> 1) * 8192 +
                                     (((wc & 1) * 4 + n) * 2 + ks) * 512 + loff];
    };

    f32x4 acc[8][4];
    #pragma unroll
    for (int m = 0; m < 8; ++m)
        #pragma unroll
        for (int n = 0; n < 4; ++n)
            acc[m][n] = (f32x4){0.f, 0.f, 0.f, 0.f};

    bf16x8 a03[4][2], a47[4][2], b01[2][2], b23[2][2];

    // prologue: tile0 (4 half-tiles, buf0) + tile1 (3 half-tiles, buf1)
    stageB(0, 0, 0); stageB(0, 1, 0); stageA(0, 0, 0); stageA(0, 1, 0);
    stageB(1, 0, 1); stageB(1, 1, 1); stageA(1, 0, 1);
    VM6();   // tile0's 8 loads retired; tile1's 6 may be in flight
    BAR();

    for (int it = 0; it < NIT; ++it) {
        const int t1  = 2 * it + 1;
        const int tp0 = (2 * it + 2) & (NKT - 1);   // wraps harmlessly on last iter
        const int tp1 = (2 * it + 3) & (NKT - 1);

        // ======== K-tile 2it from buf0 ========
        // ph1: read A0-3 + B0-1; stage A-half1 of tile 2it+1 -> buf1
        #pragma unroll
        for (int m = 0; m < 4; ++m) { a03[m][0] = ldA(0, m, 0); a03[m][1] = ldA(0, m, 1); }
        #pragma unroll
        for (int n = 0; n < 2; ++n) { b01[n][0] = ldB(0, n, 0); b01[n][1] = ldB(0, n, 1); }
        stageA(1, 1, t1);
        LGKM8();
        BAR(); LGKM0();
        QUAD(a03, b01, 0, 0);
        BAR();

        // ph2: read B2-3; stage B-half0 of tile 2it+2 -> buf0
        #pragma unroll
        for (int n = 0; n < 2; ++n) { b23[n][0] = ldB(0, 2 + n, 0); b23[n][1] = ldB(0, 2 + n, 1); }
        stageB(0, 0, tp0);
        BAR(); LGKM0();
        QUAD(a03, b23, 0, 2);
        BAR();

        // ph3: read A4-7; stage B-half1 -> buf0
        #pragma unroll
        for (int m = 0; m < 4; ++m) { a47[m][0] = ldA(0, 4 + m, 0); a47[m][1] = ldA(0, 4 + m, 1); }
        stageB(0, 1, tp0);
        BAR(); LGKM0();
        QUAD(a47, b23, 4, 2);
        BAR();

        // ph4: no reads (reuse a47,b01); stage A-half0 -> buf0; vmcnt gate
        stageA(0, 0, tp0);
        BAR(); LGKM0();
        QUAD(a47, b01, 4, 0);
        VM6();
        BAR();

        // ======== K-tile 2it+1 from buf1 ========
        // ph5: read A0-3 + B0-1; stage A-half1 of tile 2it+2 -> buf0
        #pragma unroll
        for (int m = 0; m < 4; ++m) { a03[m][0] = ldA(1, m, 0); a03[m][1] = ldA(1, m, 1); }
        #pragma unroll
        for (int n = 0; n < 2; ++n) { b01[n][0] = ldB(1, n, 0); b01[n][1] = ldB(1, n, 1); }
        stageA(0, 1, tp0);
        LGKM8();
        BAR(); LGKM0();
        QUAD(a03, b01, 0, 0);
        BAR();

        // ph6: read B2-3; stage B-half0 of tile 2it+3 -> buf1
        #pragma unroll
        for (int n = 0; n < 2; ++n) { b23[n][0] = ldB(1, 2 + n, 0); b23[n][1] = ldB(1, 2 + n, 1); }
        stageB(1, 0, tp1);
        BAR(); LGKM0();
        QUAD(a03, b23, 0, 2);
        BAR();

        // ph7: read A4-7; stage B-half1 -> buf1
        #pragma unroll
        for (int m = 0; m < 4; ++m) { a47[m][0] = ldA(1, 4 + m, 0); a47[m][1] = ldA(1, 4 + m, 1); }
        stageB(1, 1, tp1);
        BAR(); LGKM0();
        QUAD(a47, b23, 4, 2);
        BAR();

        // ph8: no reads; stage A-half0 -> buf1; vmcnt gate
        stageA(1, 0, tp1);
        BAR(); LGKM0();
        QUAD(a47, b01, 4, 0);
        VM6();
        BAR();
    }

    __syncthreads();   // all LDS reads of the main loop done; smem free for reuse

    // ---- epilogue part 1: fold bias into acc, per-row |max| -> atomicMax ----
    float bv[4];
    #pragma unroll
    for (int n = 0; n < 4; ++n)
        bv[n] = bias[bn + wc * 64 + n * 16 + lr];

    #pragma unroll
    for (int m = 0; m < 8; ++m) {
        #pragma unroll
        for (int r = 0; r < 4; ++r) {
            const int row = bm + wr * 128 + m * 16 + g * 4 + r;
            float amax = 0.f;
            #pragma unroll
            for (int n = 0; n < 4; ++n) {
                acc[m][n][r] += bv[n];                 // same FP op order as before
                amax = fmaxf(amax, fabsf(acc[m][n][r]));
            }
            #pragma unroll
            for (int off = 1; off < 16; off <<= 1)
                amax = fmaxf(amax, __shfl_xor(amax, off));
            if (lr == 0)
                atomicMax(rowmax + row, __float_as_int(amax));
        }
    }

    // ---- epilogue part 2: LDS-transposed, coalesced fp32 h store ----
    // two passes of 128 rows; LDS as float[128][256] (128 KiB)
    float* hs = (float*)smem;
    #pragma unroll
    for (int p = 0; p < 2; ++p) {
        if (p) __syncthreads();                        // protect pass-0 reads
        if (wr == p) {
            #pragma unroll
            for (int m = 0; m < 8; ++m)
                #pragma unroll
                for (int r = 0; r < 4; ++r)
                    #pragma unroll
                    for (int n = 0; n < 4; ++n)
                        hs[(m * 16 + g * 4 + r) * 256 + wc * 64 + n * 16 + lr] =
                            acc[m][n][r];
        }
        __syncthreads();
        // 128 rows x 1 KiB: 512 threads x f32x4 x 16 iters, wave = one full row
        #pragma unroll
        for (int j = 0; j < 16; ++j) {
            const int fi  = j * 2048 + t * 4;          // float index in [128][256]
            const int row = fi >> 8;
            const int col = fi & 255;
            *(f32x4*)&out[(size_t)(bm + p * 128 + row) * N + bn + col] =
                *(const f32x4*)&hs[fi];
        }
    }
}

// ---------------- quantize + ReLU (in-place, 4-deep MLP) ----------------
// nvec = 8388608 = 16 * (2048*256): exact, no tail handling needed
__global__ __launch_bounds__(256) void quant_relu(
    float* __restrict__ y, const int* __restrict__ rowmax)
{
    const int nvec = (M * N) / 4;   // 1024 float4 per row
    const int span = gridDim.x * blockDim.x;
    const int tid  = blockIdx.x * blockDim.x + threadIdx.x;

    for (int base = tid; base < nvec; base += 4 * span) {
        f32x4 v[4];
        unsigned mb[4];
        #pragma unroll
        for (int j = 0; j < 4; ++j)                    // 4 independent loads
            v[j] = ((const f32x4*)y)[base + j * span];
        #pragma unroll
        for (int j = 0; j < 4; ++j)
            mb[j] = (unsigned)rowmax[(base + j * span) >> 10];
        #pragma unroll
        for (int j = 0; j < 4; ++j) {
            // step = 2^(e-6), inv = 2^(6-e) from the exponent field of mx (>0, normal)
            const unsigned eb   = mb[j] & 0x7f800000u;
            const float    step = __uint_as_float(eb - 0x03000000u);   // e-6
            const float    inv  = __uint_as_float(0x82000000u - eb);   // 6-e
            f32x4 q;
            #pragma unroll
            for (int k = 0; k < 4; ++k) {
                const float qq = floorf(v[j][k] * inv + 0.5f) * step;
                q[k] = fmaxf(mb[j] ? qq : v[j][k], 0.f);
            }
            ((f32x4*)y)[base + j * span] = q;
        }
    }
}

extern "C" void kernel_launch(void* const* d_in, const int* in_sizes, int n_in,
                              void* d_out, int out_size, void* d_ws, size_t ws_size,
                              hipStream_t stream) {
    const float* x = (const float*)d_in[0];
    const float* w = (const float*)d_in[1];
    const float* b = (const float*)d_in[2];
    float* out = (float*)d_out;

    const size_t XB = (size_t)M * K * 2;   // 64 MiB
    const size_t WB = (size_t)N * K * 2;   // 32 MiB

    unsigned short* xb = (unsigned short*)d_ws;
    unsigned short* wb = (unsigned short*)((char*)d_ws + XB);
    int* rowmax        = (int*)((char*)d_ws + XB + WB);

    cvt_bf16_2<<<3072, 256, 0, stream>>>(x, xb, (M * K) / 4, w, wb, (N * K) / 4, rowmax);
    gemm_bf16<<<dim3((M / BM) * (N / BN)), 512, 0, stream>>>(xb, wb, b, out, rowmax);
    quant_relu<<<2048, 256, 0, stream>>>(out, rowmax);
}